// Round 3
// baseline (127.441 us; speedup 1.0000x reference)
//
#include <hip/hip_runtime.h>
#include <cstdint>
#include <climits>

#pragma clang fp contract(off)

#define NCAM 6
#define NCLS 10
#define IMGW 1600
#define IMGH 900

// XLA-style float->int32 convert: saturate out-of-range, NaN -> 0.
// (numpy on x86 would wrap to INT_MIN; tested R1/R2, gave stable absmax=9,
//  so trying the saturating semantics the JAX-produced expected would have.)
__device__ __forceinline__ int sat_f2i(float f) {
    if (f != f) return 0;
    if (f >= 2147483648.0f) return INT_MAX;
    if (f <= -2147483648.0f) return INT_MIN;
    return (int)f;
}

// One block per box. Phase 1: threads 0..5 each project the box into their
// camera -> sP[cam] = {x1,y1,x2,y2,area,valid}. Phase 2: 256 threads stride
// the M detections, accumulate iou*valid*score per class, LDS tree-reduce,
// thread 0 writes label+score.
__global__ __launch_bounds__(256) void fused_kernel(
        const float* __restrict__ boxes,   // [N][7]
        const float* __restrict__ ia,      // [6][4][4]
        const float* __restrict__ la,      // [4][4]
        const float* __restrict__ l2i,     // [6][4][4]
        const float4* __restrict__ det_boxes,
        const int*    __restrict__ det_labels,
        const float*  __restrict__ det_scores,
        const int*    __restrict__ det_batch,
        const int*    __restrict__ det_cam,
        float* __restrict__ out,           // [2*N]: labels then scores
        int N, int M) {
    int n = blockIdx.x;
    int tid = threadIdx.x;
    if (n >= N) return;

    __shared__ float sP[NCAM][6];
    __shared__ float red[NCLS][256];

    if (tid < NCAM) {
        int cam = tid;
        float bx = boxes[n*7+0], by = boxes[n*7+1], bz = boxes[n*7+2];
        float dx = boxes[n*7+3], dy = boxes[n*7+4], dz = boxes[n*7+5];
        float yaw = boxes[n*7+6];
        // correctly-rounded f32 trig via fp64 (closest match to host libm)
        float c = (float)cos((double)yaw);
        float s = (float)sin((double)yaw);

        // inverse of lidar_aug 3x3 (adjugate) + translation
        float a00=la[0],a01=la[1],a02=la[2],t0=la[3];
        float a10=la[4],a11=la[5],a12=la[6],t1=la[7];
        float a20=la[8],a21=la[9],a22=la[10],t2=la[11];
        float det = a00*(a11*a22-a12*a21) - a01*(a10*a22-a12*a20) + a02*(a10*a21-a11*a20);
        float id = 1.0f/det;
        float r00=(a11*a22-a12*a21)*id, r01=(a02*a21-a01*a22)*id, r02=(a01*a12-a02*a11)*id;
        float r10=(a12*a20-a10*a22)*id, r11=(a00*a22-a02*a20)*id, r12=(a02*a10-a00*a12)*id;
        float r20=(a10*a21-a11*a20)*id, r21=(a01*a20-a00*a21)*id, r22=(a00*a11-a01*a10)*id;

        const float* L = l2i + cam*16;
        const float* A = ia  + cam*16;
        int minx = INT_MAX, miny = INT_MAX, maxx = INT_MIN, maxy = INT_MIN;
        #pragma unroll
        for (int k = 0; k < 8; k++) {
            // CORNER_TEMPLATE signs
            float sx = ((k==0||k==1||k==4||k==5) ?  0.5f : -0.5f) * dx;
            float sy = ((k==0||k==3||k==4||k==7) ?  0.5f : -0.5f) * dy;
            float sz = ((k>=4)                   ?  0.5f : -0.5f) * dz;
            // yaw rotation: x' = sx*c - sy*s ; y' = sx*s + sy*c
            float cx = sx*c - sy*s + bx;
            float cy = sx*s + sy*c + by;
            float cz = sz + bz;
            float ux = cx - t0, uy = cy - t1, uz = cz - t2;
            float PX = r00*ux + r01*uy + r02*uz;
            float PY = r10*ux + r11*uy + r12*uz;
            float PZ = r20*ux + r21*uy + r22*uz;

            float u = L[0]*PX + L[1]*PY + L[2]*PZ  + L[3];
            float v = L[4]*PX + L[5]*PY + L[6]*PZ  + L[7];
            float w = L[8]*PX + L[9]*PY + L[10]*PZ + L[11];
            float zc = fminf(fmaxf(w, 1e-5f), 100000.0f);
            float x = u / zc, y = v / zc;   // IEEE divide
            float xx = A[0]*x + A[1]*y + A[2]*zc + A[3];
            float yy = A[4]*x + A[5]*y + A[6]*zc + A[7];
            int pxi = sat_f2i(xx); pxi = min(max(pxi, 0), IMGW);
            int pyi = sat_f2i(yy); pyi = min(max(pyi, 0), IMGH);
            minx = min(minx, pxi); maxx = max(maxx, pxi);
            miny = min(miny, pyi); maxy = max(maxy, pyi);
        }
        float x1 = (float)minx, y1 = (float)miny, x2 = (float)maxx, y2 = (float)maxy;
        float validf = ((x2 - x1) > 0.0f && (y2 - y1) > 0.0f) ? 1.0f : 0.0f;
        sP[cam][0] = x1; sP[cam][1] = y1; sP[cam][2] = x2; sP[cam][3] = y2;
        sP[cam][4] = (x2 - x1) * (y2 - y1);
        sP[cam][5] = validf;
    }
    __syncthreads();

    float probs[NCLS];
    #pragma unroll
    for (int k = 0; k < NCLS; k++) probs[k] = 0.0f;

    for (int m = tid; m < M; m += 256) {
        float4 b = det_boxes[m];
        int cam = det_cam[m];
        int bi  = det_batch[m];
        int cls = det_labels[m] - 1;
        float sc = det_scores[m];
        if (bi == 0 && cam >= 0 && cam < NCAM && cls >= 0 && cls < NCLS) {
            const float* P = sP[cam];
            float ltx = fmaxf(b.x, P[0]);
            float lty = fmaxf(b.y, P[1]);
            float rbx = fminf(b.z, P[2]);
            float rby = fminf(b.w, P[3]);
            float iw = fmaxf(rbx - ltx, 0.0f);
            float ih = fmaxf(rby - lty, 0.0f);
            float inter = iw * ih;
            float area_a = (b.z - b.x) * (b.w - b.y);
            float uni = area_a + P[4] - inter;
            float iou = (uni > 0.0f) ? (inter / uni) : 0.0f;
            float w = iou * P[5] * sc;
            #pragma unroll
            for (int k = 0; k < NCLS; k++) probs[k] += (k == cls) ? w : 0.0f;
        }
    }

    #pragma unroll
    for (int k = 0; k < NCLS; k++) red[k][tid] = probs[k];
    __syncthreads();
    for (int s = 128; s > 0; s >>= 1) {
        if (tid < s) {
            #pragma unroll
            for (int k = 0; k < NCLS; k++) red[k][tid] += red[k][tid + s];
        }
        __syncthreads();
    }
    if (tid == 0) {
        float nv = 0.0f;
        for (int c2 = 0; c2 < NCAM; c2++) nv += sP[c2][5];
        float denom = 1e-5f + nv;
        float best = -1.0f; int bestk = 0;
        #pragma unroll
        for (int k = 0; k < NCLS; k++) {
            float v = red[k][0] / denom;
            if (v > best) { best = v; bestk = k; }
        }
        out[n]     = (float)(bestk + 1);   // pred_labels = argmax + 1
        out[N + n] = best;                 // pred_scores
    }
}

extern "C" void kernel_launch(void* const* d_in, const int* in_sizes, int n_in,
                              void* d_out, int out_size, void* d_ws, size_t ws_size,
                              hipStream_t stream) {
    const float*  pred_boxes = (const float*)d_in[0];
    const float*  ia         = (const float*)d_in[1];
    const float*  la         = (const float*)d_in[2];
    const float*  l2i        = (const float*)d_in[3];
    const float4* det_boxes  = (const float4*)d_in[4];
    const int*    det_labels = (const int*)d_in[5];
    const float*  det_scores = (const float*)d_in[6];
    const int*    det_batch  = (const int*)d_in[7];
    const int*    det_cam    = (const int*)d_in[8];
    float* out = (float*)d_out;

    int N = in_sizes[0] / 7;   // 4096
    int M = in_sizes[4] / 4;   // 6144

    fused_kernel<<<N, 256, 0, stream>>>(pred_boxes, ia, la, l2i,
                                        det_boxes, det_labels, det_scores,
                                        det_batch, det_cam, out, N, M);
}